// Round 2
// baseline (4156.615 us; speedup 1.0000x reference)
//
#include <hip/hip_runtime.h>
#include <hip/hip_bf16.h>
#include <math.h>

typedef __hip_bfloat16 bf16;
typedef unsigned short ushort_t;

__device__ __forceinline__ float b2f(bf16 x){ return __bfloat162float(x); }
__device__ __forceinline__ bf16  f2b(float x){ return __float2bfloat16(x); }
__device__ __forceinline__ float bflo(unsigned u){ return __uint_as_float(u<<16); }
__device__ __forceinline__ float bfhi(unsigned u){ return __uint_as_float(u & 0xffff0000u); }
__device__ __forceinline__ float ldA(const float* p){ return *p; }
__device__ __forceinline__ float ldA(const bf16* p){ return __bfloat162float(*p); }
__device__ __forceinline__ float gelu_f(float x){ return 0.5f*x*(1.0f+erff(x*0.7071067811865475f)); }
__device__ __forceinline__ ushort_t bbits(bf16 x){ union{bf16 b; ushort_t u;} v; v.b=x; return v.u; }
__device__ __forceinline__ void unpack8(uint4 u, float* f){
  f[0]=bflo(u.x); f[1]=bfhi(u.x); f[2]=bflo(u.y); f[3]=bfhi(u.y);
  f[4]=bflo(u.z); f[5]=bfhi(u.z); f[6]=bflo(u.w); f[7]=bfhi(u.w);
}
// dual-dtype load of 8 consecutive floats: e8 = element_index/8
__device__ __forceinline__ void loadB8(const void* base, size_t e8, int isf32, float* f){
  if (isf32){
    const float4* p = (const float4*)base + e8*2;
    float4 a = p[0], b4 = p[1];
    f[0]=a.x; f[1]=a.y; f[2]=a.z; f[3]=a.w; f[4]=b4.x; f[5]=b4.y; f[6]=b4.z; f[7]=b4.w;
  } else {
    uint4 u = ((const uint4*)base)[e8]; unpack8(u,f);
  }
}

// ---------------- dtype probe: any NaN/Inf bf16 pattern => data is f32 ----------------
__global__ __launch_bounds__(256) void detect_k(const ushort_t* __restrict__ u, int* flag){
  int i = blockIdx.x*256 + threadIdx.x;
  bool bad = false;
  #pragma unroll
  for (int k=0;k<8;++k){
    ushort_t v = u[(size_t)i*8 + k];
    if ((v & 0x7F80) == 0x7F80) bad = true;
  }
  if (bad) flag[0] = 1;
}

// ---------------- input normalization to bf16 ----------------
__global__ __launch_bounds__(256) void cvt8_k(const void* __restrict__ src, bf16* __restrict__ dst,
                                              const int* __restrict__ flag, int n8){
  int i = blockIdx.x*256 + threadIdx.x;
  if (i >= n8) return;
  float f[8];
  loadB8(src, (size_t)i, *flag, f);
  __align__(16) bf16 o[8];
  #pragma unroll
  for (int t=0;t<8;++t) o[t]=f2b(f[t]);
  *(uint4*)(dst + (size_t)i*8) = *(const uint4*)o;
}

struct WTab { const void* src[27]; unsigned ofs8[27]; };
__global__ __launch_bounds__(256) void cvtw_k(WTab tab, bf16* __restrict__ dst,
                                              const int* __restrict__ flag, int total8){
  int i = blockIdx.x*256 + threadIdx.x;
  if (i >= total8) return;
  int s = 0;
  #pragma unroll 1
  for (int k=1;k<27;++k) if ((unsigned)i >= tab.ofs8[k]) s = k;
  size_t l8 = (unsigned)i - tab.ofs8[s];
  float f[8];
  loadB8(tab.src[s], l8, *flag, f);
  __align__(16) bf16 o[8];
  #pragma unroll
  for (int t=0;t<8;++t) o[t]=f2b(f[t]);
  *(uint4*)(dst + (size_t)i*8) = *(const uint4*)o;
}

// ---------------- generic GEMM: C[M,N](f32) = op(A[M,K] @ W[K,N] + bias) ----------------
// MODE 0: store  1: C += ...   2: C = gelu(...)
template<int MODE, typename TA>
__global__ __launch_bounds__(256) void gemm_k(
    const TA* __restrict__ A, const bf16* __restrict__ W,
    const bf16* __restrict__ bias, float* __restrict__ C,
    int M, int N, int K)
{
  __shared__ float As[16][132];
  __shared__ float Bs[16][132];
  const int tid = threadIdx.x;
  const int col0 = blockIdx.x*128, row0 = blockIdx.y*128;
  const int tr = tid>>4, tc = tid&15;
  float acc[8][8];
  #pragma unroll
  for (int i=0;i<8;++i)
    #pragma unroll
    for (int j=0;j<8;++j) acc[i][j]=0.f;
  for (int k0=0;k0<K;k0+=16){
    #pragma unroll
    for (int t=0;t<8;++t){
      int e = tid + 256*t;
      int mm = e>>4, kk = e&15;
      As[kk][mm] = ldA(A + (size_t)(row0+mm)*K + (k0+kk));
    }
    #pragma unroll
    for (int t=0;t<8;++t){
      int e = tid + 256*t;
      int kk = e>>7, cc = e&127;
      Bs[kk][cc] = b2f(W[(size_t)(k0+kk)*N + col0+cc]);
    }
    __syncthreads();
    #pragma unroll
    for (int kk=0;kk<16;++kk){
      float a[8], b[8];
      *(float4*)&a[0] = *(const float4*)&As[kk][tr*8];
      *(float4*)&a[4] = *(const float4*)&As[kk][tr*8+4];
      *(float4*)&b[0] = *(const float4*)&Bs[kk][tc*8];
      *(float4*)&b[4] = *(const float4*)&Bs[kk][tc*8+4];
      #pragma unroll
      for (int i=0;i<8;++i)
        #pragma unroll
        for (int j=0;j<8;++j) acc[i][j] += a[i]*b[j];
    }
    __syncthreads();
  }
  float bv[8];
  #pragma unroll
  for (int j=0;j<8;++j) bv[j] = bias ? b2f(bias[col0+tc*8+j]) : 0.f;
  #pragma unroll
  for (int i=0;i<8;++i){
    float* cp = C + (size_t)(row0+tr*8+i)*N + col0 + tc*8;
    #pragma unroll
    for (int j=0;j<8;++j){
      float v = acc[i][j] + bv[j];
      if (MODE==1) v += cp[j];
      else if (MODE==2) v = gelu_f(v);
      cp[j] = v;
    }
  }
}

// ---------------- copies ----------------
__global__ __launch_bounds__(256) void b2fcopy_k(const bf16* __restrict__ s, float* __restrict__ d, int n8){
  int i = blockIdx.x*256 + threadIdx.x;
  if (i < n8){
    uint4 u = ((const uint4*)s)[i];
    float f[8]; unpack8(u,f);
    float4* o = (float4*)(d + (size_t)i*8);
    o[0] = make_float4(f[0],f[1],f[2],f[3]);
    o[1] = make_float4(f[4],f[5],f[6],f[7]);
  }
}
__global__ __launch_bounds__(256) void f4copy_k(const float4* __restrict__ s, float4* __restrict__ d, int n4){
  int i = blockIdx.x*256 + threadIdx.x;
  if (i < n4) d[i] = s[i];
}

// ---------------- LayerNorm over 768 ----------------
__device__ __forceinline__ void ln768_body(const float* x, int tid, float& v0, float& v1, float& v2,
                                           float& u, float& rs, float* red){
  v0=x[tid]; v1=x[tid+256]; v2=x[tid+512];
  float s = v0+v1+v2, s2 = v0*v0+v1*v1+v2*v2;
  #pragma unroll
  for (int m=32;m;m>>=1){ s += __shfl_xor(s,m); s2 += __shfl_xor(s2,m); }
  if ((tid&63)==0){ red[tid>>6]=s; red[4+(tid>>6)]=s2; }
  __syncthreads();
  s = red[0]+red[1]+red[2]+red[3]; s2 = red[4]+red[5]+red[6]+red[7];
  u = s*(1.f/768.f);
  float var = s2*(1.f/768.f) - u*u;
  rs = rsqrtf(var + 1e-12f);
}
__global__ __launch_bounds__(256) void ln_mid_k(const float* __restrict__ X, float* __restrict__ Y){
  __shared__ float red[8];
  int row = blockIdx.x, tid = threadIdx.x;
  float v0,v1,v2,u,rs;
  ln768_body(X + (size_t)row*768, tid, v0,v1,v2,u,rs, red);
  float* y = Y + (size_t)row*768;
  y[tid]=(v0-u)*rs; y[tid+256]=(v1-u)*rs; y[tid+512]=(v2-u)*rs;
}
__global__ __launch_bounds__(256) void ln_out_k(const float* __restrict__ X, void* __restrict__ Y,
                                                const int* __restrict__ flag){
  __shared__ float red[8];
  int row = blockIdx.x, tid = threadIdx.x;
  float v0,v1,v2,u,rs;
  ln768_body(X + (size_t)row*768, tid, v0,v1,v2,u,rs, red);
  if (*flag){
    float* y = (float*)Y + (size_t)row*768;
    y[tid]=(v0-u)*rs; y[tid+256]=(v1-u)*rs; y[tid+512]=(v2-u)*rs;
  } else {
    bf16* y = (bf16*)Y + (size_t)row*768;
    y[tid]=f2b((v0-u)*rs); y[tid+256]=f2b((v1-u)*rs); y[tid+512]=f2b((v2-u)*rs);
  }
}

// ---------------- Join operator ----------------
__global__ __launch_bounds__(256) void join_attn_k(
  const void* __restrict__ B2v, const int* __restrict__ flag, const bf16* __restrict__ Ws,
  const float* __restrict__ v, float* __restrict__ jo_pre)
{
  __shared__ float wcol[64];
  __shared__ float sc[512];
  __shared__ float redm[4], reds[4];
  __shared__ float part[4][64];
  int blk = blockIdx.x;
  int m = blk & 511; int bh = blk >> 9; int h = bh % 12; int b = bh / 12;
  int tid = threadIdx.x;
  const int isf32 = *flag;
  if (tid < 64) wcol[tid] = b2f(Ws[tid*12 + h]);
  __syncthreads();
  size_t e8row = (size_t)(b*512+m)*4096;   // (b*512+m)*512*64/8
  float myscore[2];
  #pragma unroll
  for (int t=0;t<2;++t){
    int n = tid + 256*t;
    float acc = 0.f;
    #pragma unroll
    for (int u4=0;u4<8;++u4){
      float f[8];
      loadB8(B2v, e8row + (size_t)n*8 + u4, isf32, f);
      const float* wc = &wcol[u4*8];
      #pragma unroll
      for (int u=0;u<8;++u) acc += f[u]*wc[u];
    }
    myscore[t] = acc;
  }
  float mloc = fmaxf(myscore[0], myscore[1]);
  #pragma unroll
  for (int msk=32;msk;msk>>=1) mloc = fmaxf(mloc, __shfl_xor(mloc,msk));
  if ((tid&63)==0) redm[tid>>6] = mloc;
  __syncthreads();
  float mx = fmaxf(fmaxf(redm[0],redm[1]), fmaxf(redm[2],redm[3]));
  float e0 = expf(myscore[0]-mx), e1 = expf(myscore[1]-mx);
  sc[tid] = e0; sc[tid+256] = e1;
  float ps = e0+e1;
  #pragma unroll
  for (int msk=32;msk;msk>>=1) ps += __shfl_xor(ps,msk);
  if ((tid&63)==0) reds[tid>>6] = ps;
  __syncthreads();
  float inv = 1.0f/(reds[0]+reds[1]+reds[2]+reds[3]);
  int e = tid & 63, g = tid >> 6;
  const float* vb = v + (size_t)b*512*768 + h*64 + e;
  float acc = 0.f;
  for (int n=g; n<512; n+=4) acc += sc[n]*vb[(size_t)n*768];
  part[g][e] = acc;
  __syncthreads();
  if (tid < 64){
    float r = (part[0][tid]+part[1][tid]+part[2][tid]+part[3][tid])*inv;
    jo_pre[(size_t)(b*512+m)*768 + h*64 + tid] = r;
  }
}

// ---------------- cj: softmax over tokens n for each (b, a) ----------------
__global__ __launch_bounds__(256) void cj_softmax_k(const float* __restrict__ kraw, float* __restrict__ kers){
  __shared__ float red[8];
  int blk = blockIdx.x; int a = blk % 768; int b = blk / 768;
  int tid = threadIdx.x;
  const float* x = kraw + (size_t)b*512*768 + a;
  float v0 = x[(size_t)tid*768], v1 = x[(size_t)(tid+256)*768];
  float mloc = fmaxf(v0,v1);
  #pragma unroll
  for (int msk=32;msk;msk>>=1) mloc = fmaxf(mloc, __shfl_xor(mloc,msk));
  if ((tid&63)==0) red[tid>>6] = mloc;
  __syncthreads();
  float mx = fmaxf(fmaxf(red[0],red[1]), fmaxf(red[2],red[3]));
  float e0 = expf(v0-mx), e1 = expf(v1-mx);
  float ps = e0+e1;
  #pragma unroll
  for (int msk=32;msk;msk>>=1) ps += __shfl_xor(ps,msk);
  if ((tid&63)==0) red[4+(tid>>6)] = ps;
  __syncthreads();
  float inv = 1.0f/(red[4]+red[5]+red[6]+red[7]);
  float* o = kers + ((size_t)b*768 + a)*512;
  o[tid] = e0*inv; o[tid+256] = e1*inv;
}

// ---------------- proj64: out[b][j][r][s] = B2[b,r,s,:] . W[:,j] (+bias[j]) ----------------
__global__ __launch_bounds__(256) void proj64_k(
  const void* __restrict__ B2v, const int* __restrict__ flag,
  const bf16* __restrict__ W, int ldW,
  const bf16* __restrict__ bias, bf16* __restrict__ outp)
{
  __shared__ float Wl[64][68];
  __shared__ float Bsh[64][68];
  int blk = blockIdx.x; int r = blk & 511; int b = blk >> 9;
  int tid = threadIdx.x; int wv = tid>>6, nl = tid&63;
  const int isf32 = *flag;
  #pragma unroll
  for (int t=0;t<16;++t){
    int e = tid + 256*t; int c = e>>6, j = e&63;
    Wl[c][j] = b2f(W[c*ldW + j]);
  }
  float biasv[16];
  #pragma unroll
  for (int jj=0;jj<16;++jj) biasv[jj] = bias ? b2f(bias[wv*16+jj]) : 0.f;
  for (int si=0; si<8; ++si){
    __syncthreads();
    size_t e8base = ((size_t)(b*512+r)*512 + (size_t)si*64) * 8;
    #pragma unroll
    for (int t=0;t<2;++t){
      int idx = tid + 256*t;           // 0..511 -> 8 elems each = 64x64 tile
      float f[8];
      loadB8(B2v, e8base + idx, isf32, f);
      int rr = idx>>3, c0 = (idx&7)*8;
      #pragma unroll
      for (int u=0;u<8;++u) Bsh[rr][c0+u] = f[u];
    }
    __syncthreads();
    float acc[16];
    #pragma unroll
    for (int jj=0;jj<16;++jj) acc[jj]=0.f;
    #pragma unroll
    for (int c4=0;c4<16;++c4){
      float4 bv = *(const float4*)&Bsh[nl][c4*4];
      const float* bp = (const float*)&bv;
      #pragma unroll
      for (int u=0;u<4;++u){
        float bb = bp[u];
        const float* wrow = &Wl[c4*4+u][wv*16];
        #pragma unroll
        for (int jj=0;jj<16;++jj) acc[jj] += bb*wrow[jj];
      }
    }
    size_t obase = ((size_t)(b*64 + wv*16)*512 + r)*512 + (size_t)si*64 + nl;
    #pragma unroll
    for (int jj=0;jj<16;++jj)
      outp[obase + (size_t)jj*512*512] = f2b(acc[jj]+biasv[jj]);
  }
}

// ---------------- cj mix ----------------
__global__ __launch_bounds__(256) void cjmix_k(const float* __restrict__ kers, const bf16* __restrict__ prem, float* __restrict__ cjp){
  __shared__ float kl[512][16];
  int blk = blockIdx.x; int half = blk & 1; int d = (blk>>1)&63; int b = blk>>7;
  int tid = threadIdx.x;
  #pragma unroll
  for (int t=0;t<32;++t){
    int e = tid + 256*t;
    int hh = e>>9, m = e&511;
    float v = 0.f;
    if (hh < 12) v = kers[((size_t)b*768 + d*12 + hh)*512 + m];
    kl[m][hh] = v;
  }
  __syncthreads();
  int n = half*256 + tid;
  const bf16* pm = prem + (size_t)(b*64 + d)*512*512;
  float acc[12];
  #pragma unroll
  for (int h=0;h<12;++h) acc[h]=0.f;
  for (int m=0;m<512;++m){
    float x = b2f(pm[(size_t)m*512 + n]);
    const float* krow = kl[m];
    #pragma unroll
    for (int h=0;h<12;++h) acc[h] += x*krow[h];
  }
  float* o = cjp + (size_t)(b*512 + n)*768 + d*12;
  #pragma unroll
  for (int h=0;h<12;++h) o[h] = acc[h];
}

// ---------------- as scores ----------------
__global__ __launch_bounds__(256) void ao_scores_k(const float* __restrict__ qk, bf16* __restrict__ S){
  __shared__ float Qs[64][68], Ks[64][68];
  int blk = blockIdx.x;
  int ntile = blk & 7, mtile = (blk>>3)&7; int bh = blk>>6; int h = bh%12, b = bh/12;
  int tid = threadIdx.x;
  #pragma unroll
  for (int t=0;t<16;++t){
    int e = tid + 256*t; int rr = e>>6, ee = e&63;
    Qs[ee][rr] = qk[(size_t)(b*512 + mtile*64 + rr)*1536 + h*64 + ee];
    Ks[ee][rr] = qk[(size_t)(b*512 + ntile*64 + rr)*1536 + 768 + h*64 + ee];
  }
  __syncthreads();
  int tr = tid>>4, tc = tid&15;
  float acc[4][4];
  #pragma unroll
  for (int i=0;i<4;++i)
    #pragma unroll
    for (int j=0;j<4;++j) acc[i][j]=0.f;
  #pragma unroll 4
  for (int e=0;e<64;++e){
    float4 a = *(const float4*)&Qs[e][tr*4];
    float4 bb = *(const float4*)&Ks[e][tc*4];
    const float* ap = (const float*)&a; const float* bp = (const float*)&bb;
    #pragma unroll
    for (int i=0;i<4;++i)
      #pragma unroll
      for (int j=0;j<4;++j) acc[i][j] += ap[i]*bp[j];
  }
  #pragma unroll
  for (int i=0;i<4;++i){
    size_t rbase = ((size_t)(b*12+h)*512 + mtile*64 + tr*4+i)*512 + ntile*64 + tc*4;
    __align__(8) bf16 o4[4];
    #pragma unroll
    for (int j=0;j<4;++j) o4[j] = f2b(acc[i][j]*0.125f);
    *(uint2*)&S[rbase] = *(const uint2*)o4;
  }
}

// ---------------- row stats / exp for tq softmax ----------------
__global__ __launch_bounds__(256) void rowstats_k(const bf16* __restrict__ X, float* __restrict__ Mx, float* __restrict__ Dn){
  int row = blockIdx.x*4 + (threadIdx.x>>6);
  int lane = threadIdx.x & 63;
  const bf16* x = X + (size_t)row*512;
  float v[8]; float m = -3e38f;
  #pragma unroll
  for (int t=0;t<8;++t){ v[t] = b2f(x[lane + 64*t]); m = fmaxf(m,v[t]); }
  #pragma unroll
  for (int msk=32;msk;msk>>=1) m = fmaxf(m, __shfl_xor(m,msk));
  float s = 0.f;
  #pragma unroll
  for (int t=0;t<8;++t) s += expf(v[t]-m);
  #pragma unroll
  for (int msk=32;msk;msk>>=1) s += __shfl_xor(s,msk);
  if (lane==0){ Mx[row]=m; Dn[row]=s; }
}
__global__ __launch_bounds__(256) void expnorm_k(bf16* __restrict__ X, const float* __restrict__ Mx){
  size_t i = (size_t)blockIdx.x*256 + threadIdx.x;
  size_t row = i >> 6;
  float m = Mx[row];
  uint4* p = (uint4*)X + i;
  uint4 u = *p;
  float f[8]; unpack8(u,f);
  __align__(16) bf16 o[8];
  #pragma unroll
  for (int t=0;t<8;++t) o[t] = f2b(expf(f[t]-m));
  *p = *(const uint4*)o;
}

// ---------------- to GEMM per (b,c) ----------------
__global__ __launch_bounds__(256) void togemm_k(const bf16* __restrict__ QTe, const bf16* __restrict__ K2,
   const float* __restrict__ Dn, void* __restrict__ dout, const int* __restrict__ flag)
{
  __shared__ float As[16][132], Bs[16][132];
  const int isf32 = *flag;
  bf16* toT = (bf16*)((char*)dout + (size_t)786432*(isf32?4:2));
  int bc = blockIdx.y;
  int tm = blockIdx.x >> 2, tn = blockIdx.x & 3;
  const bf16* A = QTe + (size_t)bc*512*512;
  const bf16* Bp = K2 + (size_t)bc*512*512;
  int row0 = tm*128, col0 = tn*128;
  int tid = threadIdx.x; int tr = tid>>4, tc = tid&15;
  float acc[8][8];
  #pragma unroll
  for (int i=0;i<8;++i)
    #pragma unroll
    for (int j=0;j<8;++j) acc[i][j]=0.f;
  for (int k0=0;k0<512;k0+=16){
    #pragma unroll
    for (int t=0;t<8;++t){
      int e = tid + 256*t; int mm = e>>4, kk = e&15;
      As[kk][mm] = b2f(A[(size_t)(row0+mm)*512 + k0+kk]);
    }
    #pragma unroll
    for (int t=0;t<8;++t){
      int e = tid + 256*t; int kk = e>>7, cc = e&127;
      Bs[kk][cc] = b2f(Bp[(size_t)(k0+kk)*512 + col0+cc]);
    }
    __syncthreads();
    #pragma unroll
    for (int kk=0;kk<16;++kk){
      float a[8], b[8];
      *(float4*)&a[0] = *(const float4*)&As[kk][tr*8];
      *(float4*)&a[4] = *(const float4*)&As[kk][tr*8+4];
      *(float4*)&b[0] = *(const float4*)&Bs[kk][tc*8];
      *(float4*)&b[4] = *(const float4*)&Bs[kk][tc*8+4];
      #pragma unroll
      for (int i=0;i<8;++i)
        #pragma unroll
        for (int j=0;j<8;++j) acc[i][j] += a[i]*b[j];
    }
    __syncthreads();
  }
  #pragma unroll
  for (int i=0;i<8;++i){
    int r = row0 + tr*8 + i;
    float inv = 1.0f / Dn[(size_t)bc*512 + r];
    __align__(16) bf16 o[8];
    #pragma unroll
    for (int j=0;j<8;++j) o[j] = f2b(acc[i][j]*inv);
    *(uint4*)(toT + (size_t)bc*512*512 + (size_t)r*512 + col0 + tc*8) = *(const uint4*)o;
  }
}

// ---------------- b_mix = LN64(B2 + S_ao@asWw + toT@trWw + biases) ----------------
__global__ __launch_bounds__(128) void bmix_k(
  const void* __restrict__ B2v, const int* __restrict__ flag,
  const bf16* __restrict__ S, const void* __restrict__ dout,
  const bf16* __restrict__ asWw, const bf16* __restrict__ asbw,
  const bf16* __restrict__ trWw, const bf16* __restrict__ trbw,
  bf16* __restrict__ bmix)
{
  __shared__ float As[77][132];
  __shared__ float Bs[77][68];
  const int isf32 = *flag;
  const bf16* toT = (const bf16*)((const char*)dout + (size_t)786432*(isf32?4:2));
  int blk = blockIdx.x; int kt = blk&3; int bm = blk>>2; int m = bm&511; int b = bm>>9;
  int k0 = kt*128;
  int tid = threadIdx.x;
  for (int kk=0;kk<77;++kk){
    float v;
    if (kk<12)      v = b2f(S[((size_t)(b*12+kk)*512 + m)*512 + k0+tid]);
    else if (kk<76) v = b2f(toT[((size_t)(b*64+(kk-12))*512 + m)*512 + k0+tid]);
    else            v = 1.0f;
    As[kk][tid] = v;
  }
  for (int t=0;t<39;++t){
    int e = tid + 128*t;
    if (e < 77*64){
      int kk = e>>6, j = e&63;
      float v;
      if (kk<12)      v = b2f(asWw[kk*64 + j]);
      else if (kk<76) v = b2f(trWw[(kk-12)*64 + j]);
      else            v = b2f(asbw[j]) + b2f(trbw[j]);
      Bs[kk][j] = v;
    }
  }
  __syncthreads();
  int tr = tid>>3, tc = tid&7;
  float acc[8][8];
  #pragma unroll
  for (int i=0;i<8;++i)
    #pragma unroll
    for (int j=0;j<8;++j) acc[i][j]=0.f;
  for (int kk=0;kk<77;++kk){
    float a[8], bb[8];
    *(float4*)&a[0] = *(const float4*)&As[kk][tr*8];
    *(float4*)&a[4] = *(const float4*)&As[kk][tr*8+4];
    *(float4*)&bb[0] = *(const float4*)&Bs[kk][tc*8];
    *(float4*)&bb[4] = *(const float4*)&Bs[kk][tc*8+4];
    #pragma unroll
    for (int i=0;i<8;++i)
      #pragma unroll
      for (int j=0;j<8;++j) acc[i][j] += a[i]*bb[j];
  }
  size_t rowbase = ((size_t)(b*512+m)*512 + k0 + tr*8);
  #pragma unroll
  for (int i=0;i<8;++i){
    float f[8];
    loadB8(B2v, (rowbase+i)*8 + tc, isf32, f);
    float z[8];
    float s=0.f, s2=0.f;
    #pragma unroll
    for (int j=0;j<8;++j){ z[j] = acc[i][j] + f[j]; s += z[j]; s2 += z[j]*z[j]; }
    s += __shfl_xor(s,1); s += __shfl_xor(s,2); s += __shfl_xor(s,4);
    s2 += __shfl_xor(s2,1); s2 += __shfl_xor(s2,2); s2 += __shfl_xor(s2,4);
    float u_ = s*(1.f/64.f);
    float var = s2*(1.f/64.f) - u_*u_;
    float rs = rsqrtf(var + 1e-12f);
    __align__(16) bf16 o[8];
    #pragma unroll
    for (int j=0;j<8;++j) o[j] = f2b((z[j]-u_)*rs);
    *(uint4*)(bmix + (rowbase+i)*64 + tc*8) = *(const uint4*)o;
  }
}

// ---------------- b2 MLP fused ----------------
__global__ __launch_bounds__(256) void b2mlp_k(
  const bf16* __restrict__ bmix, const bf16* __restrict__ W1, const bf16* __restrict__ b1v,
  const bf16* __restrict__ W2, const bf16* __restrict__ b2v,
  const bf16* __restrict__ Wsm, const bf16* __restrict__ bsv,
  void* __restrict__ outp, const int* __restrict__ flag)
{
  __shared__ float Xs[128][44];
  __shared__ ushort_t Hs[256][40];
  const int isf32 = *flag;
  int blk = blockIdx.x; int kt = blk&15; int bm = blk>>4; int m = bm&511; int b = bm>>9;
  int k0 = kt*32;
  int tid = threadIdx.x;
  #pragma unroll
  for (int t=0;t<16;++t){
    int e = tid + 256*t;
    int j = e&63, r = e>>6;
    if (r < 32) Xs[j][r]       = b2f(bmix[(((size_t)(b*512+m)*512) + k0+r)*64 + j]);
    else        Xs[64+j][r-32] = b2f(bmix[(((size_t)(b*512+k0+(r-32))*512) + m)*64 + j]);
  }
  __syncthreads();
  {
    float acc[32];
    #pragma unroll
    for (int r=0;r<32;++r) acc[r]=0.f;
    float bc = b2f(b1v[tid]);
    #pragma unroll 2
    for (int f=0; f<128; ++f){
      float w = b2f(W1[f*256 + tid]);
      #pragma unroll
      for (int r4=0;r4<8;++r4){
        float4 xv = *(const float4*)&Xs[f][r4*4];
        acc[r4*4+0]+=xv.x*w; acc[r4*4+1]+=xv.y*w;
        acc[r4*4+2]+=xv.z*w; acc[r4*4+3]+=xv.w*w;
      }
    }
    #pragma unroll
    for (int r=0;r<32;++r) Hs[tid][r] = bbits(f2b(gelu_f(acc[r]+bc)));
  }
  __syncthreads();
  int rg = tid>>6, j = tid&63;
  float acc2[8];
  #pragma unroll
  for (int i=0;i<8;++i) acc2[i]=0.f;
  for (int c=0;c<256;++c){
    float w = b2f(W2[(size_t)c*64 + j]);
    uint4 h8 = *(const uint4*)&Hs[c][rg*8];
    float hf[8]; unpack8(h8,hf);
    #pragma unroll
    for (int i=0;i<8;++i) acc2[i] += hf[i]*w;
  }
  for (int e=0;e<64;++e){
    float w = b2f(Wsm[e*64 + j]);
    float4 y0 = *(const float4*)&Xs[64+e][rg*8];
    float4 y1 = *(const float4*)&Xs[64+e][rg*8+4];
    acc2[0]+=y0.x*w; acc2[1]+=y0.y*w; acc2[2]+=y0.z*w; acc2[3]+=y0.w*w;
    acc2[4]+=y1.x*w; acc2[5]+=y1.y*w; acc2[6]+=y1.z*w; acc2[7]+=y1.w*w;
  }
  float bias = b2f(b2v[j]) + b2f(bsv[j]);
  #pragma unroll
  for (int i=0;i<8;++i){
    int r = rg*8+i;
    float z = acc2[i] + bias + Xs[j][r];
    float s=z, s2=z*z;
    #pragma unroll
    for (int msk=32;msk;msk>>=1){ s += __shfl_xor(s,msk); s2 += __shfl_xor(s2,msk); }
    float u_ = s*(1.f/64.f);
    float var = s2*(1.f/64.f) - u_*u_;
    float rs = rsqrtf(var + 1e-12f);
    size_t oidx = (((size_t)(b*512+m)*512) + k0+r)*64 + j;
    float val = (z-u_)*rs;
    if (isf32) ((float*)outp)[786432 + oidx] = val;
    else       ((bf16*)outp)[786432 + oidx] = f2b(val);
  }
}

// ==========================================================================================
extern "C" void kernel_launch(void* const* d_in, const int* in_sizes, int n_in,
                              void* d_out, int out_size, void* d_ws, size_t ws_size,
                              hipStream_t stream)
{
  static const unsigned wsz[27] = {
    589824,768,768,589824,768,          // jWv jbv jWs jWw jbw
    589824,4096,64,589824,768,          // cWk cWp cbp cWo cbo
    1179648,1536,768,64,                // aWqk abqk aWw abw
    8192,4096,64,                       // tWqk tWw tbw
    2359296,3072,2359296,768,           // m1W1 m1b1 m1W2 m1b2
    32768,256,16384,64,4096,64          // m2W1 m2b1 m2W2 m2b2 m2Ws m2bs
  };
  unsigned wofs8[28]; wofs8[0]=0;
  for (int k=0;k<27;++k) wofs8[k+1] = wofs8[k] + wsz[k]/8;
  const unsigned totalW8 = wofs8[27];   // 1,042,120

  char* p = (char*)d_ws;
  auto carve = [&](size_t bytes)->char*{ char* r = p; p += (bytes+255)&~(size_t)255; return r; };
  int*  flag    = (int*)carve(256);
  bf16* Ub      = (bf16*)carve((size_t)786432*2);
  bf16* wsW     = (bf16*)carve((size_t)totalW8*8*2);
  float* v_buf  = (float*)carve((size_t)1024*768*4);
  float* jo_pre = (float*)carve((size_t)1024*768*4);
  float* ker_raw= (float*)carve((size_t)1024*768*4);
  float* kers   = (float*)carve((size_t)1024*768*4);
  float* cj_pre = (float*)carve((size_t)1024*768*4);
  float* u_pre  = (float*)carve((size_t)1024*768*4);
  float* u_mix  = (float*)carve((size_t)1024*768*4);
  float* u_res  = (float*)carve((size_t)1024*768*4);
  float* qk_buf = (float*)carve((size_t)1024*1536*4);
  float* h1_buf = (float*)carve((size_t)1024*3072*4);
  float* Mx     = (float*)carve((size_t)65536*4);
  float* Dn     = (float*)carve((size_t)65536*4);
  bf16* S_ao    = (bf16*)carve((size_t)2*12*512*512*2);
  bf16* QTe     = (bf16*)carve((size_t)2*64*512*512*2);
  bf16* K2b     = (bf16*)carve((size_t)2*64*512*512*2);
  bf16* bmixb   = K2b;                 // K2b dead after togemm; bmix written after
  if ((size_t)(p - (char*)d_ws) > ws_size) return;  // zero output signals ws shortage

  const void* B2raw = d_in[1];
  // weight pointers into the bf16 copy region
  auto Wp = [&](int k)->const bf16*{ return wsW + (size_t)wofs8[k]*8; };
  const bf16 *jWv=Wp(0), *jbv=Wp(1), *jWs=Wp(2), *jWw=Wp(3), *jbw=Wp(4),
             *cWk=Wp(5), *cWp=Wp(6), *cbp=Wp(7), *cWo=Wp(8), *cbo=Wp(9),
             *aWqk=Wp(10), *abqk=Wp(11), *aWw=Wp(12), *abw=Wp(13),
             *tWqk=Wp(14), *tWw=Wp(15), *tbw=Wp(16),
             *m1W1=Wp(17), *m1b1=Wp(18), *m1W2=Wp(19), *m1b2=Wp(20),
             *m2W1=Wp(21), *m2b1=Wp(22), *m2W2=Wp(23), *m2b2=Wp(24),
             *m2Ws=Wp(25), *m2bs=Wp(26);

  // ---- dtype probe + input normalization ----
  hipMemsetAsync(flag, 0, 4, stream);
  detect_k<<<dim3(384),256,0,stream>>>((const ushort_t*)d_in[0], flag);
  cvt8_k<<<dim3(384),256,0,stream>>>(d_in[0], Ub, flag, 98304);
  WTab tab;
  for (int k=0;k<27;++k){ tab.src[k] = d_in[2+k]; tab.ofs8[k] = wofs8[k]; }
  cvtw_k<<<dim3((totalW8+255)/256),256,0,stream>>>(tab, wsW, flag, (int)totalW8);

  // ---- join ----
  gemm_k<0,bf16><<<dim3(6,8),256,0,stream>>>(Ub, jWv, jbv, v_buf, 1024,768,768);
  join_attn_k<<<dim3(12288),256,0,stream>>>(B2raw, flag, jWs, v_buf, jo_pre);
  b2fcopy_k<<<dim3(384),256,0,stream>>>(Ub, u_pre, 98304);
  gemm_k<1,float><<<dim3(6,8),256,0,stream>>>(jo_pre, jWw, jbw, u_pre, 1024,768,768);
  // ---- conjugate join ----
  gemm_k<0,bf16><<<dim3(6,8),256,0,stream>>>(Ub, cWk, (const bf16*)nullptr, ker_raw, 1024,768,768);
  cj_softmax_k<<<dim3(1536),256,0,stream>>>(ker_raw, kers);
  proj64_k<<<dim3(1024),256,0,stream>>>(B2raw, flag, cWp, 64, cbp, QTe);     // prem
  cjmix_k<<<dim3(256),256,0,stream>>>(kers, QTe, cj_pre);
  gemm_k<1,float><<<dim3(6,8),256,0,stream>>>(cj_pre, cWo, cbo, u_pre, 1024,768,768);
  ln_mid_k<<<dim3(1024),256,0,stream>>>(u_pre, u_mix);
  // ---- associative ----
  gemm_k<0,bf16><<<dim3(12,8),256,0,stream>>>(Ub, aWqk, abqk, qk_buf, 1024,1536,768);
  ao_scores_k<<<dim3(1536),256,0,stream>>>(qk_buf, S_ao);
  // ---- composition ----
  proj64_k<<<dim3(1024),256,0,stream>>>(B2raw, flag, tWqk, 128, (const bf16*)nullptr, QTe);
  rowstats_k<<<dim3(16384),256,0,stream>>>(QTe, Mx, Dn);
  expnorm_k<<<dim3(16384),256,0,stream>>>(QTe, Mx);
  proj64_k<<<dim3(1024),256,0,stream>>>(B2raw, flag, tWqk+64, 128, (const bf16*)nullptr, K2b);
  togemm_k<<<dim3(16,128),256,0,stream>>>(QTe, K2b, Dn, d_out, flag);
  // ---- b_mix ----  (bmixb aliases K2b, dead after togemm)
  bmix_k<<<dim3(4096),128,0,stream>>>(B2raw, flag, S_ao, d_out, aWw, abw, tWw, tbw, bmixb);
  // ---- u MLP + LN -> u_out ----
  gemm_k<2,float><<<dim3(24,8),256,0,stream>>>(u_mix, m1W1, m1b1, h1_buf, 1024,3072,768);
  f4copy_k<<<dim3(768),256,0,stream>>>((const float4*)u_mix, (float4*)u_res, 196608);
  gemm_k<1,float><<<dim3(6,8),256,0,stream>>>(h1_buf, m1W2, m1b2, u_res, 1024,768,3072);
  ln_out_k<<<dim3(1024),256,0,stream>>>(u_res, d_out, flag);
  // ---- b MLP + LN -> b_out ----
  b2mlp_k<<<dim3(16384),256,0,stream>>>(bmixb, m2W1, m2b1, m2W2, m2b2, m2Ws, m2bs, d_out, flag);
}